// Round 16
// baseline (107.686 us; speedup 1.0000x reference)
//
#include <hip/hip_runtime.h>

// ---------------------------------------------------------------------------
// FeatureNet: kNN(K=8) relative grouping -> [conv1x1+BN+ReLU] x3 -> max over K
// B=8, N=2048, DIM=128, fp32 in/out.
//
// R16: ONE mega-kernel, 2048 blocks x 256 thr (4 waves), 8 queries/block.
//   Phase K (R14 logic): stage batch cands (33.3KB LDS, split float2 planes,
//     pad i+(i>>6)); 32 lanes/query x 64 cands; sort8+fold phase1 (dv[64] in
//     VGPRs); 5 shfl_xor merge rounds -> exact 8th-smallest; register-mask
//     rescan -> idx to LDS (no global round-trip).
//   Phase G (R15 logic): per-block W1/W2 bf16 hi/lo fragment conversion from
//     RAW inputs (bit-identical split3(w*s) expressions); h1 from x directly;
//     2 chunks x 32 pairs; g1 -> H(LDS) -> g2 -> max -> out.
//   No prep kernel, no ws usage, no inter-kernel sync. knn (VALU) of one
//   block overlaps gemm (MFMA) of the co-resident block (2 blocks/CU).
// LDS 70.3KB: candXY @0 16.6K | candZS @16640 16.6K (phase K)
//             A0 @0 16K | A1 @16K | H0 @32K | H1 @48K (phase G, time-shared)
//             OS @64K 4K | W0L @68K 2K | idxs @70K 256B   (persistent)
// ---------------------------------------------------------------------------

#define EPSF 1e-5f
#define FMAXV 3.402823466e+38f

#define NB 8
#define NN 2048

typedef __attribute__((ext_vector_type(4))) float f32x4;
typedef __attribute__((ext_vector_type(8))) short short8v;

__device__ __forceinline__ float relu_f(float a) { return fmaxf(a, 0.0f); }

// fp32 -> bf16(hi, RNE) + bf16(lo, trunc of residual)
__device__ __forceinline__ void split3(float f, unsigned& hi, unsigned& lo) {
  const unsigned u = __float_as_uint(f);
  const unsigned h = (u + 0x7FFFu + ((u >> 16) & 1u)) >> 16;
  const float hf = __uint_as_float(h << 16);
  lo = __float_as_uint(f - hf) >> 16;
  hi = h;
}

__device__ __forceinline__ f32x4 mfma16x16x32bf(short8v a, short8v b, f32x4 c) {
  return __builtin_amdgcn_mfma_f32_16x16x32_bf16(a, b, c, 0, 0, 0);
}

// ---- named-scalar selection primitives (R7 lesson: NO runtime-idx state) ----
#define KCSWAP(a, b)                  \
  {                                   \
    const float mn_ = fminf(a, b);    \
    const float mx_ = fmaxf(a, b);    \
    (a) = mn_; (b) = mx_;             \
  }

#define SORT8(d0, d1, d2, d3, d4, d5, d6, d7)                   \
  KCSWAP(d0, d1) KCSWAP(d2, d3) KCSWAP(d4, d5) KCSWAP(d6, d7)   \
  KCSWAP(d0, d2) KCSWAP(d1, d3) KCSWAP(d4, d6) KCSWAP(d5, d7)   \
  KCSWAP(d1, d2) KCSWAP(d5, d6)                                 \
  KCSWAP(d0, d4) KCSWAP(d1, d5) KCSWAP(d2, d6) KCSWAP(d3, d7)   \
  KCSWAP(d2, d4) KCSWAP(d3, d5)                                 \
  KCSWAP(d1, d2) KCSWAP(d3, d4) KCSWAP(d5, d6)

#define KCLEAN8()                                               \
  KCSWAP(k0, k4) KCSWAP(k1, k5) KCSWAP(k2, k6) KCSWAP(k3, k7)   \
  KCSWAP(k0, k2) KCSWAP(k1, k3) KCSWAP(k4, k6) KCSWAP(k5, k7)   \
  KCSWAP(k0, k1) KCSWAP(k2, k3) KCSWAP(k4, k5) KCSWAP(k6, k7)

#define KFOLD8(d0, d1, d2, d3, d4, d5, d6, d7)                  \
  {                                                             \
    k0 = fminf(k0, d7); k1 = fminf(k1, d6);                     \
    k2 = fminf(k2, d5); k3 = fminf(k3, d4);                     \
    k4 = fminf(k4, d3); k5 = fminf(k5, d2);                     \
    k6 = fminf(k6, d1); k7 = fminf(k7, d0);                     \
    KCLEAN8()                                                   \
  }

#define KMERGE(mv)                                              \
  {                                                             \
    const float q0_ = __shfl_xor(k0, mv, 64);                   \
    const float q1_ = __shfl_xor(k1, mv, 64);                   \
    const float q2_ = __shfl_xor(k2, mv, 64);                   \
    const float q3_ = __shfl_xor(k3, mv, 64);                   \
    const float q4_ = __shfl_xor(k4, mv, 64);                   \
    const float q5_ = __shfl_xor(k5, mv, 64);                   \
    const float q6_ = __shfl_xor(k6, mv, 64);                   \
    const float q7_ = __shfl_xor(k7, mv, 64);                   \
    k0 = fminf(k0, q7_); k1 = fminf(k1, q6_);                   \
    k2 = fminf(k2, q5_); k3 = fminf(k3, q4_);                   \
    k4 = fminf(k4, q3_); k5 = fminf(k5, q2_);                   \
    k6 = fminf(k6, q1_); k7 = fminf(k7, q0_);                   \
    KCLEAN8()                                                   \
  }

// ------------------------------ mega kernel ---------------------------------
__global__ __launch_bounds__(256, 2) void mega_kernel(
    const float* __restrict__ x, const float* __restrict__ w0,
    const float* __restrict__ b0, const float* __restrict__ wstk,
    const float* __restrict__ bstk, const float* __restrict__ g,
    const float* __restrict__ be, const float* __restrict__ bm,
    const float* __restrict__ bv, float* __restrict__ out) {
  extern __shared__ char smem[];
  float2* __restrict__ xyp = (float2*)smem;            // phase K
  float2* __restrict__ zsp = (float2*)(smem + 16640);  // phase K
  float* __restrict__ OS = (float*)(smem + 65536);     // 4KB
  float4* __restrict__ W0L = (float4*)(smem + 69632);  // 2KB
  int* __restrict__ idxs = (int*)(smem + 71680);       // 64 ints

  const int t = threadIdx.x;
  const int lane = t & 63, w = t >> 6;
  const int wc = w;  // 4 waves = 4 fo-slices of 32
  const int bid = blockIdx.x;
  const int bb = bid & 7, qseg = bid >> 3;  // qseg 0..255, 8 queries
  const float* __restrict__ xb = x + bb * 3 * NN;

  // ---- W0L: s0-folded layer0 weights + c0, perm'd (independent region) ----
  if (t < 128) {
    const float s0 = g[t] / sqrtf(bv[t] + EPSF);
    float4 wv;
    wv.x = w0[3 * t + 0] * s0;
    wv.y = w0[3 * t + 1] * s0;
    wv.z = w0[3 * t + 2] * s0;
    wv.w = (b0[t] - bm[t]) * s0 + be[t];  // c0
    W0L[((t & 7) << 4) | (t >> 3)] = wv;
  }

  // ============================ PHASE K: kNN ===============================
  // stage all 2048 candidates of this batch (pad ii = i + (i>>6))
#pragma unroll
  for (int k = 0; k < 8; ++k) {
    const int i = t + k * 256;
    const float a0 = xb[i];
    const float a1 = xb[2048 + i];
    const float a2 = xb[4096 + i];
    const float sq = fmaf(a2, a2, fmaf(a1, a1, a0 * a0));
    const int ii = i + (i >> 6);
    xyp[ii] = make_float2(a0, a1);
    zsp[ii] = make_float2(a2, sq);
  }

  const int qi = t >> 5;  // 0..7 query within block
  const int sg = t & 31;  // candidate slice
  const int n = qseg * 8 + qi;
  const float qx0 = xb[n], qx1 = xb[2048 + n], qx2 = xb[4096 + n];
  const float sqn = fmaf(qx2, qx2, fmaf(qx1, qx1, qx0 * qx0));
  __syncthreads();

  {
    const float2* __restrict__ xr = xyp + sg * 65;
    const float2* __restrict__ zr = zsp + sg * 65;

    // phase 1: 8 batches of sort-8 + fold; all 64 distances in VGPRs
    float dv[64];
    float k0 = FMAXV, k1 = FMAXV, k2 = FMAXV, k3 = FMAXV,
          k4 = FMAXV, k5 = FMAXV, k6 = FMAXV, k7 = FMAXV;
#pragma unroll
    for (int bt = 0; bt < 8; ++bt) {
      float d0, d1, d2, d3, d4, d5, d6, d7;
#define KD(j, dj)                                                        \
      {                                                                  \
        const float2 cxy = xr[bt * 8 + (j)];                             \
        const float2 czs = zr[bt * 8 + (j)];                             \
        const float inner =                                              \
            fmaf(qx2, czs.x, fmaf(qx1, cxy.y, qx0 * cxy.x));             \
        dj = (sqn - 2.0f * inner) + czs.y;                               \
      }
      KD(0, d0) KD(1, d1) KD(2, d2) KD(3, d3)
      KD(4, d4) KD(5, d5) KD(6, d6) KD(7, d7)
#undef KD
      dv[bt * 8 + 0] = d0; dv[bt * 8 + 1] = d1;
      dv[bt * 8 + 2] = d2; dv[bt * 8 + 3] = d3;
      dv[bt * 8 + 4] = d4; dv[bt * 8 + 5] = d5;
      dv[bt * 8 + 6] = d6; dv[bt * 8 + 7] = d7;
      SORT8(d0, d1, d2, d3, d4, d5, d6, d7)
      KFOLD8(d0, d1, d2, d3, d4, d5, d6, d7)
    }

    // cross-lane merge: 32 lanes -> exact global 8th-smallest
    KMERGE(1) KMERGE(2) KMERGE(4) KMERGE(8) KMERGE(16)
    const float thr = k7;

    // phase 2: register compare-only rescan
    unsigned am = 0, bm2 = 0;
#pragma unroll
    for (int mm = 0; mm < 32; ++mm) am |= (dv[mm] <= thr) ? (1u << mm) : 0u;
#pragma unroll
    for (int mm = 0; mm < 32; ++mm)
      bm2 |= (dv[32 + mm] <= thr) ? (1u << mm) : 0u;

    // exclusive scan of counts over the 32-lane group
    const int cnt = __popc(am) + __popc(bm2);
    int inc = cnt, tq;
    tq = __shfl_up(inc, 1, 32); inc += (sg >= 1) ? tq : 0;
    tq = __shfl_up(inc, 2, 32); inc += (sg >= 2) ? tq : 0;
    tq = __shfl_up(inc, 4, 32); inc += (sg >= 4) ? tq : 0;
    tq = __shfl_up(inc, 8, 32); inc += (sg >= 8) ? tq : 0;
    tq = __shfl_up(inc, 16, 32); inc += (sg >= 16) ? tq : 0;
    int pos = inc - cnt;

    // extraction: first 8 hits (ascending cand index) -> LDS idxs
    {
      unsigned wv = am;
      while (wv) {
        const int b = __ffs(wv) - 1;
        wv &= wv - 1;
        if (pos < 8) idxs[qi * 8 + pos] = sg * 64 + b;
        ++pos;
      }
      wv = bm2;
      while (wv) {
        const int b = __ffs(wv) - 1;
        wv &= wv - 1;
        if (pos < 8) idxs[qi * 8 + pos] = sg * 64 + 32 + b;
        ++pos;
      }
    }
  }
  __syncthreads();  // idxs visible; candidate LDS now dead -> reuse as A/H

  // ============================ PHASE G: gemms =============================
  // W1/W2 fragments from RAW inputs (bit-identical to old prep expressions)
  short8v w1h[2][4], w1l[2][4], w2h[2][4], w2l[2][4];
#pragma unroll
  for (int ft = 0; ft < 2; ++ft) {
    const int fo = wc * 32 + ft * 16 + (lane & 15);
    const float s1 = g[128 + fo] / sqrtf(bv[128 + fo] + EPSF);
    const float s2 = g[256 + fo] / sqrtf(bv[256 + fo] + EPSF);
#pragma unroll
    for (int ks = 0; ks < 4; ++ks) {
      const int kb = ks * 32 + (lane >> 4) * 8;
      const float4 a1 = *(const float4*)(wstk + fo * 128 + kb);
      const float4 b1 = *(const float4*)(wstk + fo * 128 + kb + 4);
      const float4 a2 = *(const float4*)(wstk + 16384 + fo * 128 + kb);
      const float4 b2 = *(const float4*)(wstk + 16384 + fo * 128 + kb + 4);
      const float v1[8] = {a1.x, a1.y, a1.z, a1.w, b1.x, b1.y, b1.z, b1.w};
      const float v2[8] = {a2.x, a2.y, a2.z, a2.w, b2.x, b2.y, b2.z, b2.w};
      short8v h1v, l1v, h2v, l2v;
#pragma unroll
      for (int e = 0; e < 8; ++e) {
        unsigned hh, ll;
        split3(v1[e] * s1, hh, ll);
        h1v[e] = (short)hh; l1v[e] = (short)ll;
        split3(v2[e] * s2, hh, ll);
        h2v[e] = (short)hh; l2v[e] = (short)ll;
      }
      w1h[ft][ks] = h1v; w1l[ft][ks] = l1v;
      w2h[ft][ks] = h2v; w2l[ft][ks] = l2v;
    }
  }
  float c1v0, c1v1, c2v0, c2v1;
  {
    const int foA = wc * 32 + (lane & 15), foB = foA + 16;
    const float s1A = g[128 + foA] / sqrtf(bv[128 + foA] + EPSF);
    const float s1B = g[128 + foB] / sqrtf(bv[128 + foB] + EPSF);
    const float s2A = g[256 + foA] / sqrtf(bv[256 + foA] + EPSF);
    const float s2B = g[256 + foB] / sqrtf(bv[256 + foB] + EPSF);
    c1v0 = (bstk[foA] - bm[128 + foA]) * s1A + be[128 + foA];
    c1v1 = (bstk[foB] - bm[128 + foB]) * s1B + be[128 + foB];
    c2v0 = (bstk[128 + foA] - bm[256 + foA]) * s2A + be[256 + foA];
    c2v1 = (bstk[128 + foB] - bm[256 + foB]) * s2B + be[256 + foB];
  }

  const int row = t >> 3, part8 = t & 7;

#define PACK_WRITE_A(base, hv, kc)                              \
  {                                                             \
    unsigned hh[8], ll[8];                                      \
    _Pragma("unroll") for (int e = 0; e < 8; ++e)               \
        split3(hv[e], hh[e], ll[e]);                            \
    int4 hp, lp;                                                \
    hp.x = (int)(hh[0] | (hh[1] << 16));                        \
    hp.y = (int)(hh[2] | (hh[3] << 16));                        \
    hp.z = (int)(hh[4] | (hh[5] << 16));                        \
    hp.w = (int)(hh[6] | (hh[7] << 16));                        \
    lp.x = (int)(ll[0] | (ll[1] << 16));                        \
    lp.y = (int)(ll[2] | (ll[3] << 16));                        \
    lp.z = (int)(ll[4] | (ll[5] << 16));                        \
    lp.w = (int)(ll[6] | (ll[7] << 16));                        \
    const int col = (kc) ^ (row & 7);                           \
    *(int4*)((base) + row * 256 + col * 16) = hp;               \
    *(int4*)((base) + 8192 + row * 256 + col * 16) = lp;        \
  }

#define STAGE_A(base, R0, R1, R2)                               \
  {                                                             \
    float hv0[8], hv1[8];                                       \
    _Pragma("unroll") for (int e = 0; e < 8; ++e) {             \
      const float4 wa = W0L[e * 16 + part8 * 2];                \
      const float4 wb = W0L[e * 16 + part8 * 2 + 1];            \
      hv0[e] = relu_f(                                          \
          fmaf(wa.z, R2, fmaf(wa.y, R1, fmaf(wa.x, R0, wa.w))));\
      hv1[e] = relu_f(                                          \
          fmaf(wb.z, R2, fmaf(wb.y, R1, fmaf(wb.x, R0, wb.w))));\
    }                                                           \
    PACK_WRITE_A(base, hv0, part8 * 2)                          \
    PACK_WRITE_A(base, hv1, part8 * 2 + 1)                      \
  }

#define G1_TO_H(Abase, Hbase)                                           \
  {                                                                     \
    f32x4 acc[2][2];                                                    \
    _Pragma("unroll") for (int pt = 0; pt < 2; ++pt)                    \
        _Pragma("unroll") for (int ft = 0; ft < 2; ++ft)                \
            acc[pt][ft] = (f32x4){0.f, 0.f, 0.f, 0.f};                  \
    __builtin_amdgcn_s_setprio(1);                                      \
    _Pragma("unroll") for (int ks = 0; ks < 4; ++ks) {                  \
      const int kc = ks * 4 + (lane >> 4);                              \
      _Pragma("unroll") for (int pt = 0; pt < 2; ++pt) {                \
        const int arow = pt * 16 + (lane & 15);                         \
        const int col = kc ^ (arow & 7);                                \
        const short8v ah =                                              \
            *(const short8v*)((Abase) + arow * 256 + col * 16);         \
        const short8v al =                                              \
            *(const short8v*)((Abase) + 8192 + arow * 256 + col * 16);  \
        _Pragma("unroll") for (int ft = 0; ft < 2; ++ft) {              \
          acc[pt][ft] = mfma16x16x32bf(al, w1h[ft][ks], acc[pt][ft]);   \
          acc[pt][ft] = mfma16x16x32bf(ah, w1l[ft][ks], acc[pt][ft]);   \
          acc[pt][ft] = mfma16x16x32bf(ah, w1h[ft][ks], acc[pt][ft]);   \
        }                                                               \
      }                                                                 \
    }                                                                   \
    __builtin_amdgcn_s_setprio(0);                                      \
    unsigned* __restrict__ Hp = (unsigned*)(Hbase);                     \
    _Pragma("unroll") for (int pt = 0; pt < 2; ++pt)                    \
        _Pragma("unroll") for (int ft = 0; ft < 2; ++ft) {              \
      const int fo = wc * 32 + ft * 16 + (lane & 15);                   \
      const int cc = fo >> 2;                                           \
      const float cb = ft ? c1v1 : c1v0;                                \
      _Pragma("unroll") for (int reg = 0; reg < 4; ++reg) {             \
        const int p = pt * 16 + (lane >> 4) * 4 + reg;                  \
        const float vv = relu_f(acc[pt][ft][reg] + cb);                 \
        unsigned hh, ll;                                                \
        split3(vv, hh, ll);                                             \
        Hp[p * 128 + ((cc ^ (p & 7)) << 2) + (fo & 3)] = (hh << 16) | ll; \
      }                                                                 \
    }                                                                   \
  }

#define G2_TO_OS(Hbase, CH)                                             \
  {                                                                     \
    const unsigned* __restrict__ Hp = (const unsigned*)(Hbase);         \
    f32x4 acc2[2][2];                                                   \
    _Pragma("unroll") for (int pt = 0; pt < 2; ++pt)                    \
        _Pragma("unroll") for (int ft = 0; ft < 2; ++ft)                \
            acc2[pt][ft] = (f32x4){0.f, 0.f, 0.f, 0.f};                 \
    __builtin_amdgcn_s_setprio(1);                                      \
    _Pragma("unroll") for (int ks = 0; ks < 4; ++ks) {                  \
      const int cc0 = ks * 8 + (lane >> 4) * 2;                         \
      _Pragma("unroll") for (int pt = 0; pt < 2; ++pt) {                \
        const int p = pt * 16 + (lane & 15);                            \
        const int4 u0 = *(const int4*)&Hp[p * 128 + ((cc0 ^ (p & 7)) << 2)]; \
        const int4 u1 =                                                 \
            *(const int4*)&Hp[p * 128 + (((cc0 + 1) ^ (p & 7)) << 2)];  \
        const unsigned uu[8] = {(unsigned)u0.x, (unsigned)u0.y,         \
                                (unsigned)u0.z, (unsigned)u0.w,         \
                                (unsigned)u1.x, (unsigned)u1.y,         \
                                (unsigned)u1.z, (unsigned)u1.w};        \
        short8v ah, al;                                                 \
        _Pragma("unroll") for (int e = 0; e < 8; ++e) {                 \
          ah[e] = (short)(uu[e] >> 16);                                 \
          al[e] = (short)(uu[e] & 0xFFFFu);                             \
        }                                                               \
        _Pragma("unroll") for (int ft = 0; ft < 2; ++ft) {              \
          acc2[pt][ft] = mfma16x16x32bf(al, w2h[ft][ks], acc2[pt][ft]); \
          acc2[pt][ft] = mfma16x16x32bf(ah, w2l[ft][ks], acc2[pt][ft]); \
          acc2[pt][ft] = mfma16x16x32bf(ah, w2h[ft][ks], acc2[pt][ft]); \
        }                                                               \
      }                                                                 \
    }                                                                   \
    __builtin_amdgcn_s_setprio(0);                                      \
    const int gg = lane >> 4;                                           \
    _Pragma("unroll") for (int pt = 0; pt < 2; ++pt)                    \
        _Pragma("unroll") for (int ft = 0; ft < 2; ++ft) {              \
      const int fo = wc * 32 + ft * 16 + (lane & 15);                   \
      const float cb = ft ? c2v1 : c2v0;                                \
      const float v0 = relu_f(acc2[pt][ft][0] + cb);                    \
      const float v1 = relu_f(acc2[pt][ft][1] + cb);                    \
      const float v2 = relu_f(acc2[pt][ft][2] + cb);                    \
      const float v3 = relu_f(acc2[pt][ft][3] + cb);                    \
      float m = fmaxf(fmaxf(v0, v1), fmaxf(v2, v3));                    \
      m = fmaxf(m, __shfl_xor(m, 16, 64));                              \
      if ((gg & 1) == 0) {                                              \
        const int qloc = pt * 2 + (gg >> 1);                            \
        OS[((CH) * 4 + qloc) * 128 + fo] = m;                          \
      }                                                                 \
    }                                                                   \
  }

// rel coords for chunk c (0/1): pair pl, query nloc, neighbor from LDS idxs
#define LOAD_R(C, R0, R1, R2)                                  \
  {                                                            \
    const int pl = (qseg * 2 + (C)) * 32 + row;                \
    const int nloc = pl >> 3;                                  \
    const int mloc = idxs[(nloc - qseg * 8) * 8 + (pl & 7)];   \
    R0 = xb[mloc] - xb[nloc];                                  \
    R1 = xb[2048 + mloc] - xb[2048 + nloc];                    \
    R2 = xb[4096 + mloc] - xb[4096 + nloc];                    \
  }

  // ---- 2-chunk schedule ----
  {
    float r0, r1, r2;
    LOAD_R(0, r0, r1, r2)
    STAGE_A(smem, r0, r1, r2)  // A0 @0
  }
  __syncthreads();  // A0 ready
  G1_TO_H(smem, smem + 32768)  // A0 -> H0
  {
    float r0, r1, r2;
    LOAD_R(1, r0, r1, r2)
    STAGE_A(smem + 16384, r0, r1, r2)  // A1
  }
  __syncthreads();  // H0, A1 ready
  G2_TO_OS(smem + 32768, 0)
  G1_TO_H(smem + 16384, smem + 49152)  // A1 -> H1
  __syncthreads();  // H1 ready, OS(ch0) settled
  G2_TO_OS(smem + 49152, 1)
  __syncthreads();  // OS complete

  // ---- out-write: OS[8][128] -> out[bb][f][qseg*8..] ----
  {
    const int f = t >> 1, sh = t & 1;
    float* __restrict__ op =
        out + (long)(bb * 128 + f) * 2048 + qseg * 8 + sh * 4;
    float4 o;
    o.x = OS[(sh * 4 + 0) * 128 + f];
    o.y = OS[(sh * 4 + 1) * 128 + f];
    o.z = OS[(sh * 4 + 2) * 128 + f];
    o.w = OS[(sh * 4 + 3) * 128 + f];
    *(float4*)op = o;
  }
}

// ------------------------------- launch ------------------------------------
extern "C" void kernel_launch(void* const* d_in, const int* in_sizes, int n_in,
                              void* d_out, int out_size, void* d_ws,
                              size_t ws_size, hipStream_t stream) {
  (void)in_sizes; (void)n_in; (void)out_size; (void)d_ws; (void)ws_size;
  const float* x = (const float*)d_in[0];
  const float* w0 = (const float*)d_in[1];
  const float* b0 = (const float*)d_in[2];
  const float* wst = (const float*)d_in[3];
  const float* bst = (const float*)d_in[4];
  const float* g = (const float*)d_in[5];
  const float* be = (const float*)d_in[6];
  const float* bm = (const float*)d_in[7];
  const float* bv = (const float*)d_in[8];
  float* out = (float*)d_out;

  hipFuncSetAttribute((const void*)mega_kernel,
                      hipFuncAttributeMaxDynamicSharedMemorySize, 71936);

  mega_kernel<<<2048, 256, 71936, stream>>>(x, w0, b0, wst, bst, g, be, bm,
                                            bv, out);
}

// Round 17
// 59.126 us; speedup vs baseline: 1.8213x; 1.8213x over previous
//
#include <hip/hip_runtime.h>

// ---------------------------------------------------------------------------
// FeatureNet: kNN(K=8) relative grouping -> [conv1x1+BN+ReLU] x3 -> max over K
// B=8, N=2048, DIM=128, fp32 in/out.
//
// R17 == R15 (best known, 59.4us). R16's mega-kernel fusion regressed 1.8x:
// per-block W-fragment conversion (~770 ops/thread x 2048 blocks) and 2x
// candidate-staging redundancy swamped the saved launch gap. Two-kernel
// decomposition restored.
//
// knn  : 1056 blocks x 512 thr; batch staged once; sort8+fold phase1 (dv[64]
//        in VGPRs); 5 merge rounds -> exact threshold; register-mask rescan ->
//        idx[q][8]; prep blocks 1024+ (W planes + C1/C2 + W0F4).
// fused: ONE barrier per chunk; A and H double-buffered; h1 from x directly;
//        W in 128 VGPRs; OS 16 queries flushed twice; setprio on MFMA
//        clusters. LDS 74KB -> 2 blocks/CU.
// ---------------------------------------------------------------------------

#define EPSF 1e-5f
#define FMAXV 3.402823466e+38f

#define NB 8
#define NN 2048
#define KNBR 8
#define DIMF 128
#define NQ (NB * NN)        // 16384
#define NPAIR (NQ * KNBR)   // 131072

// ws layout. W planes in u16 units [0, 65536) == floats [0, 32768).
#define OFF16_W1H 0          // 16384 u16 (fragment order)
#define OFF16_W1L 16384
#define OFF16_W2H 32768
#define OFF16_W2L 49152
#define OFF_C1 32896         // float units
#define OFF_C2 33024
#define OFF_W0F 33152        // 512 floats: [f][4] = (w0*s0 x3, c0)
#define OFF_IDX 33792        // 131072 ints

typedef __attribute__((ext_vector_type(4))) float f32x4;
typedef __attribute__((ext_vector_type(8))) short short8v;

__device__ __forceinline__ float relu_f(float a) { return fmaxf(a, 0.0f); }

// fp32 -> bf16(hi, RNE) + bf16(lo, trunc of residual)
__device__ __forceinline__ void split3(float f, unsigned& hi, unsigned& lo) {
  const unsigned u = __float_as_uint(f);
  const unsigned h = (u + 0x7FFFu + ((u >> 16) & 1u)) >> 16;
  const float hf = __uint_as_float(h << 16);
  lo = __float_as_uint(f - hf) >> 16;
  hi = h;
}

__device__ __forceinline__ f32x4 mfma16x16x32bf(short8v a, short8v b, f32x4 c) {
  return __builtin_amdgcn_mfma_f32_16x16x32_bf16(a, b, c, 0, 0, 0);
}

// ---- named-scalar selection primitives (R7 lesson: NO runtime-idx state) ----
#define KCSWAP(a, b)                  \
  {                                   \
    const float mn_ = fminf(a, b);    \
    const float mx_ = fmaxf(a, b);    \
    (a) = mn_; (b) = mx_;             \
  }

// Batcher odd-even mergesort of 8 keys (19 comparators), ascending
#define SORT8(d0, d1, d2, d3, d4, d5, d6, d7)                   \
  KCSWAP(d0, d1) KCSWAP(d2, d3) KCSWAP(d4, d5) KCSWAP(d6, d7)   \
  KCSWAP(d0, d2) KCSWAP(d1, d3) KCSWAP(d4, d6) KCSWAP(d5, d7)   \
  KCSWAP(d1, d2) KCSWAP(d5, d6)                                 \
  KCSWAP(d0, d4) KCSWAP(d1, d5) KCSWAP(d2, d6) KCSWAP(d3, d7)   \
  KCSWAP(d2, d4) KCSWAP(d3, d5)                                 \
  KCSWAP(d1, d2) KCSWAP(d3, d4) KCSWAP(d5, d6)

// 3-stage bitonic cleanup of a bitonic 8-seq in k0..k7 (sorts ascending)
#define KCLEAN8()                                               \
  KCSWAP(k0, k4) KCSWAP(k1, k5) KCSWAP(k2, k6) KCSWAP(k3, k7)   \
  KCSWAP(k0, k2) KCSWAP(k1, k3) KCSWAP(k4, k6) KCSWAP(k5, k7)   \
  KCSWAP(k0, k1) KCSWAP(k2, k3) KCSWAP(k4, k5) KCSWAP(k6, k7)

// fold sorted d0..d7 into sorted chain k0..k7 (keep low 8 of union)
#define KFOLD8(d0, d1, d2, d3, d4, d5, d6, d7)                  \
  {                                                             \
    k0 = fminf(k0, d7); k1 = fminf(k1, d6);                     \
    k2 = fminf(k2, d5); k3 = fminf(k3, d4);                     \
    k4 = fminf(k4, d3); k5 = fminf(k5, d2);                     \
    k6 = fminf(k6, d1); k7 = fminf(k7, d0);                     \
    KCLEAN8()                                                   \
  }

// Batcher merge with xor-partner's sorted 8 (both sides converge)
#define KMERGE(mv)                                              \
  {                                                             \
    const float q0_ = __shfl_xor(k0, mv, 64);                   \
    const float q1_ = __shfl_xor(k1, mv, 64);                   \
    const float q2_ = __shfl_xor(k2, mv, 64);                   \
    const float q3_ = __shfl_xor(k3, mv, 64);                   \
    const float q4_ = __shfl_xor(k4, mv, 64);                   \
    const float q5_ = __shfl_xor(k5, mv, 64);                   \
    const float q6_ = __shfl_xor(k6, mv, 64);                   \
    const float q7_ = __shfl_xor(k7, mv, 64);                   \
    k0 = fminf(k0, q7_); k1 = fminf(k1, q6_);                   \
    k2 = fminf(k2, q5_); k3 = fminf(k3, q4_);                   \
    k4 = fminf(k4, q3_); k5 = fminf(k5, q2_);                   \
    k6 = fminf(k6, q1_); k7 = fminf(k7, q0_);                   \
    KCLEAN8()                                                   \
  }

// ------------------------- knn (+prep blocks) -------------------------------
__global__ __launch_bounds__(512, 4) void knn_kernel(
    const float* __restrict__ x, const float* __restrict__ w0,
    const float* __restrict__ b0, const float* __restrict__ wstk,
    const float* __restrict__ bstk, const float* __restrict__ g,
    const float* __restrict__ be, const float* __restrict__ bm,
    const float* __restrict__ bv, float* __restrict__ ws) {
  __shared__ float2 xyp[2080];
  __shared__ float2 zsp[2080];
  const int t = threadIdx.x;
  const int bid = blockIdx.x;  // 1056

  if (bid >= 1024) {  // ---- prep path ----
    const int i = (bid - 1024) * 512 + t;  // 16384
    unsigned short* __restrict__ wsh = (unsigned short*)ws;
    const int fo = i >> 7, k = i & 127;
    const float s1 = g[128 + fo] / sqrtf(bv[128 + fo] + EPSF);
    const float s2 = g[256 + fo] / sqrtf(bv[256 + fo] + EPSF);
    unsigned h1, l1, h2, l2;
    split3(wstk[i] * s1, h1, l1);
    split3(wstk[16384 + i] * s2, h2, l2);
    const int dst = ((fo >> 4) * 4 + (k >> 5)) * 512 +
                    (((k >> 3) & 3) * 16 + (fo & 15)) * 8 + (k & 7);
    wsh[OFF16_W1H + dst] = (unsigned short)h1;
    wsh[OFF16_W1L + dst] = (unsigned short)l1;
    wsh[OFF16_W2H + dst] = (unsigned short)h2;
    wsh[OFF16_W2L + dst] = (unsigned short)l2;
    if (bid == 1024 && t < 128) {
      const int f = t;
      const float s0 = g[f] / sqrtf(bv[f] + EPSF);
      const float s1b = g[128 + f] / sqrtf(bv[128 + f] + EPSF);
      const float s2b = g[256 + f] / sqrtf(bv[256 + f] + EPSF);
      ws[OFF_C1 + f] = (bstk[f] - bm[128 + f]) * s1b + be[128 + f];
      ws[OFF_C2 + f] = (bstk[128 + f] - bm[256 + f]) * s2b + be[256 + f];
      float4 wv;
      wv.x = w0[3 * f + 0] * s0;
      wv.y = w0[3 * f + 1] * s0;
      wv.z = w0[3 * f + 2] * s0;
      wv.w = (b0[f] - bm[f]) * s0 + be[f];  // c0
      *((float4*)(ws + OFF_W0F) + f) = wv;
    }
    return;
  }

  const int bb = bid >> 7;
  const int qloc0 = (bid & 127) * 16;
  const float* __restrict__ xb = x + bb * 3 * NN;

  // ---- stage whole batch once ----
#pragma unroll
  for (int k = 0; k < 4; ++k) {
    const int i = t + k * 512;
    const float a0 = xb[i];
    const float a1 = xb[2048 + i];
    const float a2 = xb[4096 + i];
    const float sq = fmaf(a2, a2, fmaf(a1, a1, a0 * a0));
    const int ii = i + (i >> 6);
    xyp[ii] = make_float2(a0, a1);
    zsp[ii] = make_float2(a2, sq);
  }

  const int qi = t >> 5;   // 0..15
  const int sg = t & 31;   // slice
  const int n = qloc0 + qi;
  const int q = bb * NN + n;
  const float qx0 = xb[n], qx1 = xb[2048 + n], qx2 = xb[4096 + n];
  const float sqn = fmaf(qx2, qx2, fmaf(qx1, qx1, qx0 * qx0));
  __syncthreads();

  const float2* __restrict__ xr = xyp + sg * 65;
  const float2* __restrict__ zr = zsp + sg * 65;

  // ---- phase 1: 8 batches of sort-8 + fold; keep ALL distances in VGPRs ----
  float dv[64];
  float k0 = FMAXV, k1 = FMAXV, k2 = FMAXV, k3 = FMAXV,
        k4 = FMAXV, k5 = FMAXV, k6 = FMAXV, k7 = FMAXV;
#pragma unroll
  for (int bt = 0; bt < 8; ++bt) {
    float d0, d1, d2, d3, d4, d5, d6, d7;
#define KD(j, dj)                                                        \
    {                                                                    \
      const float2 cxy = xr[bt * 8 + (j)];                               \
      const float2 czs = zr[bt * 8 + (j)];                               \
      const float inner =                                                \
          fmaf(qx2, czs.x, fmaf(qx1, cxy.y, qx0 * cxy.x));               \
      dj = (sqn - 2.0f * inner) + czs.y;                                 \
    }
    KD(0, d0) KD(1, d1) KD(2, d2) KD(3, d3)
    KD(4, d4) KD(5, d5) KD(6, d6) KD(7, d7)
#undef KD
    dv[bt * 8 + 0] = d0; dv[bt * 8 + 1] = d1;
    dv[bt * 8 + 2] = d2; dv[bt * 8 + 3] = d3;
    dv[bt * 8 + 4] = d4; dv[bt * 8 + 5] = d5;
    dv[bt * 8 + 6] = d6; dv[bt * 8 + 7] = d7;
    SORT8(d0, d1, d2, d3, d4, d5, d6, d7)
    KFOLD8(d0, d1, d2, d3, d4, d5, d6, d7)
  }

  // ---- cross-lane merge: 32 lanes -> exact global 8th-smallest ----
  KMERGE(1) KMERGE(2) KMERGE(4) KMERGE(8) KMERGE(16)
  const float thr = k7;

  // ---- phase 2: register compare-only rescan ----
  unsigned am = 0, bm2 = 0;
#pragma unroll
  for (int mm = 0; mm < 32; ++mm) am |= (dv[mm] <= thr) ? (1u << mm) : 0u;
#pragma unroll
  for (int mm = 0; mm < 32; ++mm)
    bm2 |= (dv[32 + mm] <= thr) ? (1u << mm) : 0u;

  // ---- exclusive scan of per-lane counts over the 32-lane group ----
  const int cnt = __popc(am) + __popc(bm2);
  int inc = cnt, tq;
  tq = __shfl_up(inc, 1, 32); inc += (sg >= 1) ? tq : 0;
  tq = __shfl_up(inc, 2, 32); inc += (sg >= 2) ? tq : 0;
  tq = __shfl_up(inc, 4, 32); inc += (sg >= 4) ? tq : 0;
  tq = __shfl_up(inc, 8, 32); inc += (sg >= 8) ? tq : 0;
  tq = __shfl_up(inc, 16, 32); inc += (sg >= 16) ? tq : 0;
  int pos = inc - cnt;

  // ---- extraction: hits in ascending candidate index (lane-major) ----
  int* __restrict__ idxg = (int*)(ws + OFF_IDX);
  {
    unsigned w = am;
    while (w) {
      const int b = __ffs(w) - 1;
      w &= w - 1;
      if (pos < 8) idxg[q * 8 + pos] = bb * NN + sg * 64 + b;
      ++pos;
    }
    w = bm2;
    while (w) {
      const int b = __ffs(w) - 1;
      w &= w - 1;
      if (pos < 8) idxg[q * 8 + pos] = bb * NN + sg * 64 + 32 + b;
      ++pos;
    }
  }
}

// --------------------------- persistent fused ------------------------------
// 512 blocks x 256 thr (4 waves, wc=w). Block: batch bb=bid&7,
// qseg=bid>>3 (32 queries), 8 chunks of 32 pairs. ONE barrier per chunk.
// LDS 74KB: A0 @0, A1 @16K (each hi8K+lo8K), H0 @32K, H1 @48K,
//           OS(16q) @64K (8KB), W0L @72K (2KB). 2 blocks/CU.
__global__ __launch_bounds__(256, 2) void fused_kernel(
    const float* __restrict__ x, float* __restrict__ ws,
    float* __restrict__ out) {
  extern __shared__ char smem[];
  float* __restrict__ OS = (float*)(smem + 65536);
  float4* __restrict__ W0L = (float4*)(smem + 73728);

  const int* __restrict__ idxg = (const int*)(ws + OFF_IDX);
  const unsigned short* __restrict__ wsu = (const unsigned short*)ws;

  const int t = threadIdx.x;
  const int lane = t & 63, w = t >> 6;
  const int wc = w;
  const int bid = blockIdx.x;
  const int bb = bid & 7, qseg = bid >> 3;
  const int chunk0 = bb * 512 + qseg * 8;
  const float* __restrict__ xb = x + bb * 3 * NN;

  // ---- W0F4 -> LDS, perm(f) = ((f&7)<<4)|(f>>3) ----
  if (t < 128) {
    const float4 wv = *((const float4*)(ws + OFF_W0F) + t);
    W0L[((t & 7) << 4) | (t >> 3)] = wv;
  }

  // ---- W fragments -> registers ----
  short8v w1h[2][4], w1l[2][4], w2h[2][4], w2l[2][4];
#pragma unroll
  for (int ft = 0; ft < 2; ++ft)
#pragma unroll
    for (int ks = 0; ks < 4; ++ks) {
      const int off = ((wc * 2 + ft) * 4 + ks) * 512 + lane * 8;
      w1h[ft][ks] = *(const short8v*)(wsu + OFF16_W1H + off);
      w1l[ft][ks] = *(const short8v*)(wsu + OFF16_W1L + off);
      w2h[ft][ks] = *(const short8v*)(wsu + OFF16_W2H + off);
      w2l[ft][ks] = *(const short8v*)(wsu + OFF16_W2L + off);
    }

  const float c1v0 = (ws + OFF_C1)[wc * 32 + (lane & 15)];
  const float c1v1 = (ws + OFF_C1)[wc * 32 + 16 + (lane & 15)];
  const float c2v0 = (ws + OFF_C2)[wc * 32 + (lane & 15)];
  const float c2v1 = (ws + OFF_C2)[wc * 32 + 16 + (lane & 15)];

  const int row = t >> 3, part8 = t & 7;
  __syncthreads();  // W0L ready

// pack 8 floats into hi/lo int4, write swizzled (lo plane at +8192)
#define PACK_WRITE_A(base, hv, kc)                              \
  {                                                             \
    unsigned hh[8], ll[8];                                      \
    _Pragma("unroll") for (int e = 0; e < 8; ++e)               \
        split3(hv[e], hh[e], ll[e]);                            \
    int4 hp, lp;                                                \
    hp.x = (int)(hh[0] | (hh[1] << 16));                        \
    hp.y = (int)(hh[2] | (hh[3] << 16));                        \
    hp.z = (int)(hh[4] | (hh[5] << 16));                        \
    hp.w = (int)(hh[6] | (hh[7] << 16));                        \
    lp.x = (int)(ll[0] | (ll[1] << 16));                        \
    lp.y = (int)(ll[2] | (ll[3] << 16));                        \
    lp.z = (int)(ll[4] | (ll[5] << 16));                        \
    lp.w = (int)(ll[6] | (ll[7] << 16));                        \
    const int col = (kc) ^ (row & 7);                           \
    *(int4*)((base) + row * 256 + col * 16) = hp;               \
    *(int4*)((base) + 8192 + row * 256 + col * 16) = lp;        \
  }

// compute h1 (16 feats) from rel coords + W0L, pack into A plane
#define STAGE_A(base, R0, R1, R2)                               \
  {                                                             \
    float hv0[8], hv1[8];                                       \
    _Pragma("unroll") for (int e = 0; e < 8; ++e) {             \
      const float4 wa = W0L[e * 16 + part8 * 2];                \
      const float4 wb = W0L[e * 16 + part8 * 2 + 1];            \
      hv0[e] = relu_f(                                          \
          fmaf(wa.z, R2, fmaf(wa.y, R1, fmaf(wa.x, R0, wa.w))));\
      hv1[e] = relu_f(                                          \
          fmaf(wb.z, R2, fmaf(wb.y, R1, fmaf(wb.x, R0, wb.w))));\
    }                                                           \
    PACK_WRITE_A(base, hv0, part8 * 2)                          \
    PACK_WRITE_A(base, hv1, part8 * 2 + 1)                      \
  }

// g1 MFMA on A buffer -> write H buffer (relu(acc+c1) packed u32, swizzled)
#define G1_TO_H(Abase, Hbase)                                           \
  {                                                                     \
    f32x4 acc[2][2];                                                    \
    _Pragma("unroll") for (int pt = 0; pt < 2; ++pt)                    \
        _Pragma("unroll") for (int ft = 0; ft < 2; ++ft)                \
            acc[pt][ft] = (f32x4){0.f, 0.f, 0.f, 0.f};                  \
    __builtin_amdgcn_s_setprio(1);                                      \
    _Pragma("unroll") for (int ks = 0; ks < 4; ++ks) {                  \
      const int kc = ks * 4 + (lane >> 4);                              \
      _Pragma("unroll") for (int pt = 0; pt < 2; ++pt) {                \
        const int arow = pt * 16 + (lane & 15);                         \
        const int col = kc ^ (arow & 7);                                \
        const short8v ah =                                              \
            *(const short8v*)((Abase) + arow * 256 + col * 16);         \
        const short8v al =                                              \
            *(const short8v*)((Abase) + 8192 + arow * 256 + col * 16);  \
        _Pragma("unroll") for (int ft = 0; ft < 2; ++ft) {              \
          acc[pt][ft] = mfma16x16x32bf(al, w1h[ft][ks], acc[pt][ft]);   \
          acc[pt][ft] = mfma16x16x32bf(ah, w1l[ft][ks], acc[pt][ft]);   \
          acc[pt][ft] = mfma16x16x32bf(ah, w1h[ft][ks], acc[pt][ft]);   \
        }                                                               \
      }                                                                 \
    }                                                                   \
    __builtin_amdgcn_s_setprio(0);                                      \
    unsigned* __restrict__ Hp = (unsigned*)(Hbase);                     \
    _Pragma("unroll") for (int pt = 0; pt < 2; ++pt)                    \
        _Pragma("unroll") for (int ft = 0; ft < 2; ++ft) {              \
      const int fo = wc * 32 + ft * 16 + (lane & 15);                   \
      const int cc = fo >> 2;                                           \
      const float cb = ft ? c1v1 : c1v0;                                \
      _Pragma("unroll") for (int reg = 0; reg < 4; ++reg) {             \
        const int p = pt * 16 + (lane >> 4) * 4 + reg;                  \
        const float vv = relu_f(acc[pt][ft][reg] + cb);                 \
        unsigned hh, ll;                                                \
        split3(vv, hh, ll);                                             \
        Hp[p * 128 + ((cc ^ (p & 7)) << 2) + (fo & 3)] = (hh << 16) | ll; \
      }                                                                 \
    }                                                                   \
  }

// g2 MFMA on H buffer -> relu+max -> OS rows (CH&3)*4
#define G2_TO_OS(Hbase, CH)                                             \
  {                                                                     \
    const unsigned* __restrict__ Hp = (const unsigned*)(Hbase);         \
    f32x4 acc2[2][2];                                                   \
    _Pragma("unroll") for (int pt = 0; pt < 2; ++pt)                    \
        _Pragma("unroll") for (int ft = 0; ft < 2; ++ft)                \
            acc2[pt][ft] = (f32x4){0.f, 0.f, 0.f, 0.f};                 \
    __builtin_amdgcn_s_setprio(1);                                      \
    _Pragma("unroll") for (int ks = 0; ks < 4; ++ks) {                  \
      const int cc0 = ks * 8 + (lane >> 4) * 2;                         \
      _Pragma("unroll") for (int pt = 0; pt < 2; ++pt) {                \
        const int p = pt * 16 + (lane & 15);                            \
        const int4 u0 = *(const int4*)&Hp[p * 128 + ((cc0 ^ (p & 7)) << 2)]; \
        const int4 u1 =                                                 \
            *(const int4*)&Hp[p * 128 + (((cc0 + 1) ^ (p & 7)) << 2)];  \
        const unsigned uu[8] = {(unsigned)u0.x, (unsigned)u0.y,         \
                                (unsigned)u0.z, (unsigned)u0.w,         \
                                (unsigned)u1.x, (unsigned)u1.y,         \
                                (unsigned)u1.z, (unsigned)u1.w};        \
        short8v ah, al;                                                 \
        _Pragma("unroll") for (int e = 0; e < 8; ++e) {                 \
          ah[e] = (short)(uu[e] >> 16);                                 \
          al[e] = (short)(uu[e] & 0xFFFFu);                             \
        }                                                               \
        _Pragma("unroll") for (int ft = 0; ft < 2; ++ft) {              \
          acc2[pt][ft] = mfma16x16x32bf(al, w2h[ft][ks], acc2[pt][ft]); \
          acc2[pt][ft] = mfma16x16x32bf(ah, w2l[ft][ks], acc2[pt][ft]); \
          acc2[pt][ft] = mfma16x16x32bf(ah, w2h[ft][ks], acc2[pt][ft]); \
        }                                                               \
      }                                                                 \
    }                                                                   \
    __builtin_amdgcn_s_setprio(0);                                      \
    const int g = lane >> 4;                                            \
    _Pragma("unroll") for (int pt = 0; pt < 2; ++pt)                    \
        _Pragma("unroll") for (int ft = 0; ft < 2; ++ft) {              \
      const int fo = wc * 32 + ft * 16 + (lane & 15);                   \
      const float cb = ft ? c2v1 : c2v0;                                \
      const float v0 = relu_f(acc2[pt][ft][0] + cb);                    \
      const float v1 = relu_f(acc2[pt][ft][1] + cb);                    \
      const float v2 = relu_f(acc2[pt][ft][2] + cb);                    \
      const float v3 = relu_f(acc2[pt][ft][3] + cb);                    \
      float m = fmaxf(fmaxf(v0, v1), fmaxf(v2, v3));                    \
      m = fmaxf(m, __shfl_xor(m, 16, 64));                              \
      if ((g & 1) == 0) {                                               \
        const int qloc = pt * 2 + (g >> 1);                             \
        OS[(((CH) & 3) * 4 + qloc) * 128 + fo] = m;                     \
      }                                                                 \
    }                                                                   \
  }

// write OS half h (queries qseg*32 + h*16 .. +16)
#define OS_FLUSH(h)                                                     \
  {                                                                     \
    const int f = t >> 1, sh = t & 1;                                   \
    float* __restrict__ op = out + (long)(bb * 128 + f) * 2048 +        \
                             qseg * 32 + (h) * 16 + sh * 8;             \
    float4 o1, o2;                                                      \
    o1.x = OS[(sh * 8 + 0) * 128 + f];                                  \
    o1.y = OS[(sh * 8 + 1) * 128 + f];                                  \
    o1.z = OS[(sh * 8 + 2) * 128 + f];                                  \
    o1.w = OS[(sh * 8 + 3) * 128 + f];                                  \
    o2.x = OS[(sh * 8 + 4) * 128 + f];                                  \
    o2.y = OS[(sh * 8 + 5) * 128 + f];                                  \
    o2.z = OS[(sh * 8 + 6) * 128 + f];                                  \
    o2.w = OS[(sh * 8 + 7) * 128 + f];                                  \
    *(float4*)op = o1;                                                  \
    *(float4*)(op + 4) = o2;                                            \
  }

#define LOAD_R(CH, MG, R0, R1, R2)                     \
  {                                                    \
    const int mloc = (MG) & 2047;                      \
    const int nloc = ((((CH) * 32 + row)) >> 3) & 2047;\
    R0 = xb[mloc] - xb[nloc];                          \
    R1 = xb[2048 + mloc] - xb[2048 + nloc];            \
    R2 = xb[4096 + mloc] - xb[4096 + nloc];            \
  }

  // ---- prologue ----
  {
    const int mg0 = idxg[(chunk0 + 0) * 32 + row];
    const int mg1 = idxg[(chunk0 + 1) * 32 + row];
    float r0, r1, r2;
    LOAD_R(chunk0 + 0, mg0, r0, r1, r2)
    STAGE_A(smem, r0, r1, r2)
    __syncthreads();  // A0 ready
    G1_TO_H(smem, smem + 32768)  // chunk0: A0 -> H0
    LOAD_R(chunk0 + 1, mg1, r0, r1, r2)
    STAGE_A(smem + 16384, r0, r1, r2)  // A1 <- chunk1
    __syncthreads();  // H0, A1 ready
  }

  // ---- main loop: one barrier per chunk ----
#pragma unroll 1
  for (int j = 0; j < 8; ++j) {
    // prefetch idx for chunk j+2 (covered by the 96-MFMA cluster below)
    int mg2 = 0;
    if (j < 6) mg2 = idxg[(chunk0 + j + 2) * 32 + row];

    G2_TO_OS(smem + 32768 + (j & 1) * 16384, j)  // g2 chunk j from H[j&1]

    if (j < 7) {
      G1_TO_H(smem + ((j + 1) & 1) * 16384,
              smem + 32768 + ((j + 1) & 1) * 16384)  // chunk j+1
      if (j < 6) {
        float r0, r1, r2;
        LOAD_R(chunk0 + j + 2, mg2, r0, r1, r2)
        STAGE_A(smem + (j & 1) * 16384, r0, r1, r2)  // A[j&1] <- chunk j+2
      }
    }
    __syncthreads();
    if (j == 3) {
      OS_FLUSH(0)
      __syncthreads();
    }
  }
  OS_FLUSH(1)
}

// ------------------------------- launch ------------------------------------
extern "C" void kernel_launch(void* const* d_in, const int* in_sizes, int n_in,
                              void* d_out, int out_size, void* d_ws,
                              size_t ws_size, hipStream_t stream) {
  (void)in_sizes; (void)n_in; (void)out_size; (void)ws_size;
  const float* x = (const float*)d_in[0];
  const float* w0 = (const float*)d_in[1];
  const float* b0 = (const float*)d_in[2];
  const float* wst = (const float*)d_in[3];
  const float* bst = (const float*)d_in[4];
  const float* g = (const float*)d_in[5];
  const float* be = (const float*)d_in[6];
  const float* bm = (const float*)d_in[7];
  const float* bv = (const float*)d_in[8];
  float* out = (float*)d_out;
  float* ws = (float*)d_ws;

  hipFuncSetAttribute((const void*)fused_kernel,
                      hipFuncAttributeMaxDynamicSharedMemorySize, 75776);

  knn_kernel<<<1056, 512, 0, stream>>>(x, w0, b0, wst, bst, g, be, bm, bv, ws);
  fused_kernel<<<512, 256, 75776, stream>>>(x, ws, out);
}